// Round 5
// baseline (467.581 us; speedup 1.0000x reference)
//
#include <hip/hip_runtime.h>
#include <math.h>

// ---------------------------------------------------------------------------
// VQVAEZMultiScale round 5.
//   match_bulk v2: 128 rows x 256 codes per block (2 half-passes over codes).
//     A: loaded per-wave directly from feat f32 global, split to bf16 hi/lo in
//        registers (no A LDS, no bank conflicts, split done 2x not 4x).
//     B: pre-swizzled in global to exact MFMA lane layout (lane*8 shorts),
//        staged to LDS double-buffered; all ds ops are lane*16B sequential.
//   rescue_exact v2: 16 rows/block batched (codebook L2 traffic /16), fp64.
//   EPS_V tightened 1e-3 -> 2e-4 (error rms ~3e-7, worst ~3e-6: >=60x margin).
// Workspace (float units), total ~50.4 MB:
//   feat   f32[43008][256]           @ 0
//   cb_sw  bf16[2][2][32][8][512]    @ 11010048  (book,plane,T,kc,lane*8+j)
//   part   [75776][2] float4         @ 11272192
//   prob   f32[43008]                @ 11878400
//   idx1   int[43008]                @ 11921408
//   idx2   int[32768]                @ 11964416
//   cnf    f32[1024]                 @ 11997184
//   cnd    double[1024]              @ 11998208
//   img1   f32[393216]               @ 12000256
//   img2   f32[98304]                @ 12393472
//   rlistA int[43008]                @ 12491776
//   rlistB int[32768]                @ 12534784
//   dlist  int[32768]                @ 12567552
//   cnt    int[4]                    @ 12600320
// Output: out0 @0, zidx @8388608 (as float), ste0 @8454144 (all f32, NCHW)
// ---------------------------------------------------------------------------

#define FEAT_OFF   0
#define CBSW_OFF   11010048
#define PART_OFF   11272192
#define PROB_OFF   11878400
#define IDX1_OFF   11921408
#define IDX2_OFF   11964416
#define CNF_OFF    11997184
#define CND_OFF    11998208
#define IMG1_OFF   12000256
#define IMG2_OFF   12393472
#define RLA_OFF    12491776
#define RLB_OFF    12534784
#define DLIST_OFF  12567552
#define CNT_OFF    12600320

#define EPS_V 2e-4f
#define EPS_P_REL 2e-3f

typedef __attribute__((ext_vector_type(8))) short short8;
typedef __attribute__((ext_vector_type(4))) float f32x4;

__device__ inline unsigned short f2bf(float x) {
    unsigned u = __float_as_uint(x);
    return (unsigned short)((u + 0x7FFFu + ((u >> 16) & 1u)) >> 16);
}
__device__ inline float bf2f(unsigned short h) {
    return __uint_as_float(((unsigned)h) << 16);
}

__global__ void zero_cnt(int* cnt) { if (threadIdx.x < 4) cnt[threadIdx.x] = 0; }

// ---- bilinear downsample (reference order: H-average first, then W)
__global__ void ds_kernel(const float* __restrict__ img, float* __restrict__ out,
                          int Hout, int Wout, int o, int f) {
    int i = blockIdx.x * blockDim.x + threadIdx.x;
    if (i >= 8 * 3 * Hout * Wout) return;
    int x = i % Wout;
    int t = i / Wout;
    int y = t % Hout;
    int bc = t / Hout;
    const float* base = img + ((size_t)bc * 256 + (size_t)(y * f + o)) * 256;
    int cx = x * f + o;
    float v00 = base[cx],     v10 = base[256 + cx];
    float v01 = base[cx + 1], v11 = base[256 + cx + 1];
    out[i] = ((v00 + v10) * 0.5f + (v01 + v11) * 0.5f) * 0.5f;
}

// ---- per-code squared norms, fp64 + f32 copies
__global__ void cnorm_kernel(const float* __restrict__ cb, double* __restrict__ cnd,
                             float* __restrict__ cnf) {
    int row = blockIdx.x;                    // 0..1023
    const float* p = cb + (size_t)row * 256;
    int lane = threadIdx.x;                  // 64
    double s = 0.0;
    for (int c = lane; c < 256; c += 64) {
        double v = (double)p[c];
        s = fma(v, v, s);
    }
    #pragma unroll
    for (int off = 32; off; off >>= 1) s += __shfl_down(s, off);
    if (lane == 0) { cnd[row] = s; cnf[row] = (float)s; }
}

// ---- split codebooks into bf16 hi/lo, pre-swizzled to MFMA B-fragment layout:
//      cb_sw[book][p][T=code>>4][kc=ch>>5][lane*8+j],
//      lane = (code&15) + ((ch>>3)&3)*16, j = ch&7.
__global__ void split_cb(const float* __restrict__ codebooks, unsigned short* __restrict__ cbs) {
    int gid = blockIdx.x * 256 + threadIdx.x;    // over 2*512*32 = 32768 groups
    if (gid >= 32768) return;
    int book = gid >> 14, rem = gid & 16383;
    int code = rem >> 5, cg = rem & 31;          // cg = chgroup (8 ch each)
    const float* src = codebooks + (size_t)book * 131072 + (size_t)code * 256 + cg * 8;
    float4 fa = *(const float4*)src;
    float4 fb = *(const float4*)(src + 4);
    float e[8] = {fa.x, fa.y, fa.z, fa.w, fb.x, fb.y, fb.z, fb.w};
    ushort4 h0a, h0b, h1a, h1b;
    unsigned short* p0 = (unsigned short*)&h0a;  // contiguous 8 shorts h0a,h0b
    unsigned short* p1 = (unsigned short*)&h1a;
    unsigned short tmp0[8], tmp1[8];
    #pragma unroll
    for (int j = 0; j < 8; j++) {
        unsigned short h = f2bf(e[j]);
        tmp0[j] = h;
        tmp1[j] = f2bf(e[j] - bf2f(h));
    }
    (void)p0; (void)p1; (void)h0b; (void)h1b;
    int T = code >> 4, kc = cg >> 2;
    int lane = (code & 15) + (cg & 3) * 16;
    size_t off0 = ((((size_t)(book * 2 + 0)) * 32 + T) * 8 + kc) * 512 + lane * 8;
    size_t off1 = ((((size_t)(book * 2 + 1)) * 32 + T) * 8 + kc) * 512 + lane * 8;
    *(uint4*)(cbs + off0) = *(const uint4*)tmp0;
    *(uint4*)(cbs + off1) = *(const uint4*)tmp1;
}

// ---- stride-4 patchify conv, all 3 scales in one launch (round-2-proven math)
__launch_bounds__(256)
__global__ void encode_all(const float* __restrict__ image,
                           const float* __restrict__ img1,
                           const float* __restrict__ img2,
                           const float* __restrict__ w,
                           const float* __restrict__ bias,
                           float* __restrict__ feat) {
    __shared__ float patch[12 * 256];
    int bid = blockIdx.x;
    const float* img; int Hout, rowbase, local;
    if (bid < 512)      { img = image; Hout = 64; rowbase = 0;     local = bid; }
    else if (bid < 768) { img = img1;  Hout = 32; rowbase = 32768; local = bid - 512; }
    else                { img = img2;  Hout = 16; rowbase = 40960; local = bid - 768; }
    int Wout = Hout;
    int tid = threadIdx.x;
    int b = local / Hout, y = local % Hout;
    int Himg = Hout * 4, Wimg = Wout * 4;

    const float* ibase = img + (size_t)b * 3 * Himg * Wimg;
    int nload = 12 * Wimg;
    for (int i = tid; i < nload; i += 256) {
        int col = i % Wimg, r = i / Wimg;
        int ci = r >> 2, kh = r & 3;
        patch[r * Wimg + col] = ibase[((size_t)ci * Himg + 4 * y + kh) * Wimg + col];
    }
    float wr[48];
    #pragma unroll
    for (int j = 0; j < 48; j++) wr[j] = w[tid * 48 + j];
    float bv = bias[tid];
    __syncthreads();

    int rb = rowbase + (b * Hout + y) * Wout;
    for (int x = 0; x < Wout; x++) {
        float acc = 0.f;
        #pragma unroll
        for (int ci = 0; ci < 3; ci++)
            #pragma unroll
            for (int kh = 0; kh < 4; kh++) {
                const float* pr = &patch[(ci * 4 + kh) * Wimg + 4 * x];
                #pragma unroll
                for (int kw = 0; kw < 4; kw++)
                    acc = fmaf(pr[kw], wr[ci * 16 + kh * 4 + kw], acc);
            }
        feat[(size_t)(rb + x) * 256 + tid] = acc + bv;
    }
}

// ---- bulk MFMA match v2. Grid 1184 = 592 rowtiles x 2 code-halves.
//      Block: 4 waves; wave w owns rows w*32..w*32+31 (2 rt tiles), 256 codes.
__launch_bounds__(256, 2)
__global__ void match_bulk(const float* __restrict__ feat,
                           const unsigned short* __restrict__ cb_sw,
                           const float* __restrict__ cnf,
                           float* __restrict__ partials) {
    __shared__ unsigned short Bs[2][2][16][512];   // [buf][plane][ct][lane*8+j] = 64 KB
    int bid = blockIdx.x;
    int half = bid & 1, rowtile = bid >> 1;
    int book = (rowtile >= 336) ? 1 : 0;
    int frow0 = book ? (rowtile - 336) * 128 : rowtile * 128;
    int vr0 = rowtile * 128;
    int tid = threadIdx.x;
    int w = tid >> 6, l = tid & 63;
    int lm = l & 15, quad = l >> 4;
    int half16 = half * 16;

    const unsigned short* cbb = cb_sw + (size_t)book * 262144;   // [p][T][kc][512]

    f32x4 acc[2][16];
    #pragma unroll
    for (int rt = 0; rt < 2; rt++)
        #pragma unroll
        for (int ct = 0; ct < 16; ct++) acc[rt][ct] = (f32x4)0.0f;

    // A row pointers (feat f32, split in registers per kc)
    const float* arow0 = feat + (size_t)(frow0 + w * 32 + lm) * 256;
    const float* arow1 = arow0 + 16 * 256;

    // stage kc=0 into buf 0
    #pragma unroll
    for (int it = 0; it < 8; it++) {
        int chunk = it * 4 + w;
        int p = chunk >> 4, ct = chunk & 15;
        const unsigned short* src = cbb + ((((size_t)p * 32 + half16 + ct) * 8 + 0) * 512) + (size_t)l * 8;
        *(uint4*)&Bs[0][p][ct][l * 8] = *(const uint4*)src;
    }

    for (int kc = 0; kc < 8; kc++) {
        int cur = kc & 1;
        // A fragments for this kc (global, independent of barrier)
        short8 a0[2], a1[2];
        #pragma unroll
        for (int rt = 0; rt < 2; rt++) {
            const float* fp = (rt ? arow1 : arow0) + kc * 32 + quad * 8;
            float4 fa = *(const float4*)fp;
            float4 fb = *(const float4*)(fp + 4);
            float e[8] = {fa.x, fa.y, fa.z, fa.w, fb.x, fb.y, fb.z, fb.w};
            #pragma unroll
            for (int j = 0; j < 8; j++) {
                unsigned short h = f2bf(e[j]);
                a0[rt][j] = (short)h;
                a1[rt][j] = (short)f2bf(e[j] - bf2f(h));
            }
        }
        __syncthreads();                        // Bs[cur] ready; Bs[cur^1] free
        if (kc < 7) {
            #pragma unroll
            for (int it = 0; it < 8; it++) {
                int chunk = it * 4 + w;
                int p = chunk >> 4, ct = chunk & 15;
                const unsigned short* src = cbb + ((((size_t)p * 32 + half16 + ct) * 8 + (kc + 1)) * 512) + (size_t)l * 8;
                *(uint4*)&Bs[cur ^ 1][p][ct][l * 8] = *(const uint4*)src;
            }
        }
        #pragma unroll
        for (int ct = 0; ct < 16; ct++) {
            short8 b0 = *(const short8*)&Bs[cur][0][ct][l * 8];
            short8 b1 = *(const short8*)&Bs[cur][1][ct][l * 8];
            #pragma unroll
            for (int rt = 0; rt < 2; rt++) {
                acc[rt][ct] = __builtin_amdgcn_mfma_f32_16x16x32_bf16(a0[rt], b0, acc[rt][ct], 0, 0, 0);
                acc[rt][ct] = __builtin_amdgcn_mfma_f32_16x16x32_bf16(a0[rt], b1, acc[rt][ct], 0, 0, 0);
                acc[rt][ct] = __builtin_amdgcn_mfma_f32_16x16x32_bf16(a1[rt], b0, acc[rt][ct], 0, 0, 0);
            }
        }
    }

    // epilogue: v = 2*dot - ||c||^2; per row top2/argmax/sumexp over 256 codes
    float cn[16];
    #pragma unroll
    for (int ct = 0; ct < 16; ct++)
        cn[ct] = cnf[book * 512 + half * 256 + ct * 16 + lm];
    float4* part4 = (float4*)partials;

    #pragma unroll
    for (int rt = 0; rt < 2; rt++) {
        #pragma unroll
        for (int j = 0; j < 4; j++) {
            float v[16];
            #pragma unroll
            for (int ct = 0; ct < 16; ct++)
                v[ct] = 2.0f * acc[rt][ct][j] - cn[ct];
            float m1 = v[0], m2 = -3.4e38f;
            int k1 = half * 256 + lm;            // ct=0
            #pragma unroll
            for (int ct = 1; ct < 16; ct++) {
                int kk = half * 256 + ct * 16 + lm;
                if (v[ct] > m1) { m2 = m1; m1 = v[ct]; k1 = kk; }
                else m2 = fmaxf(m2, v[ct]);
            }
            float S = 0.f;
            #pragma unroll
            for (int ct = 0; ct < 16; ct++) S += expf(v[ct] - m1);
            // butterfly over the 16 lanes of this quad (codes differ by lm)
            #pragma unroll
            for (int off = 1; off < 16; off <<= 1) {
                float om1 = __shfl_xor(m1, off);
                float om2 = __shfl_xor(m2, off);
                int   ok1 = __shfl_xor(k1, off);
                float oS  = __shfl_xor(S, off);
                if (om1 > m1 || (om1 == m1 && ok1 < k1)) {
                    m2 = fmaxf(m1, om2);
                    S = oS + S * expf(m1 - om1);
                    m1 = om1; k1 = ok1;
                } else {
                    m2 = fmaxf(m2, om1);
                    S = S + oS * expf(om1 - m1);
                }
            }
            if (lm == 0) {
                int vr = vr0 + w * 32 + rt * 16 + quad * 4 + j;
                part4[(size_t)vr * 2 + half] = make_float4(m1, m2, __int_as_float(k1), S);
            }
        }
    }
}

// ---- combine the 2 half partials; write idx/prob; flag rescues per book
__global__ void combine_rows(const float* __restrict__ partials,
                             int* __restrict__ idx1, int* __restrict__ idx2,
                             float* __restrict__ prob,
                             int* __restrict__ rlistA, int* __restrict__ rlistB,
                             int* __restrict__ cnt) {
    int vr = blockIdx.x * 256 + threadIdx.x;      // grid 296*256 = 75776 exact
    const float4* p = (const float4*)partials + (size_t)vr * 2;
    float4 P0 = p[0], P1 = p[1];
    float m1, m2, S; int k1;
    if (P1.x > P0.x) {          // ties keep half0 (smaller codes)
        m1 = P1.x; k1 = __float_as_int(P1.z);
        m2 = fmaxf(P1.y, P0.x);
        S = P1.w + P0.w * expf(P0.x - P1.x);
    } else {
        m1 = P0.x; k1 = __float_as_int(P0.z);
        m2 = fmaxf(P0.y, P1.x);
        S = P0.w + P1.w * expf(P1.x - P0.x);
    }
    if (vr < 43008) { idx1[vr] = k1; prob[vr] = 1.0f / S; }
    else idx2[vr - 43008] = k1;
    if (m1 - m2 < EPS_V) {
        if (vr < 43008) { int pos = atomicAdd(cnt + 0, 1); rlistA[pos] = vr; }
        else            { int pos = atomicAdd(cnt + 2, 1); rlistB[pos] = vr - 43008; }
    }
}

// ---- exact fp64 recompute, batched 16 rows/block (codebook reuse x16)
__launch_bounds__(256)
__global__ void rescue_batch(const float* __restrict__ feat,
                             const float* __restrict__ codebooks,
                             const double* __restrict__ cnd,
                             const int* __restrict__ rlistA, const int* __restrict__ rlistB,
                             const int* __restrict__ cnt,
                             int* __restrict__ idx1, int* __restrict__ idx2,
                             float* __restrict__ prob) {
    __shared__ double rowsd[16][256];
    __shared__ double redm[4][16]; __shared__ int redk[4][16]; __shared__ double reds[4][16];
    __shared__ double gmS[16]; __shared__ int gkS[16];
    int tid = threadIdx.x;
    int lane = tid & 63, wave = tid >> 6;

    for (int listi = 0; listi < 2; listi++) {
        const int* rl = listi ? rlistB : rlistA;
        int n = cnt[listi ? 2 : 0];
        const float* cb = codebooks + (size_t)listi * 131072;
        const double* cnb = cnd + listi * 512;
        for (int base = blockIdx.x * 16; base < n; base += gridDim.x * 16) {
            int nrows = min(16, n - base);
            #pragma unroll
            for (int r = 0; r < 16; r++) {
                int fr = rl[base + ((r < nrows) ? r : 0)];
                rowsd[r][tid] = (double)feat[(size_t)fr * 256 + tid];
            }
            __syncthreads();
            double a0[16], a1[16];
            #pragma unroll
            for (int r = 0; r < 16; r++) { a0[r] = 0.0; a1[r] = 0.0; }
            const float* c0p = cb + (size_t)tid * 256;
            const float* c1p = cb + (size_t)(tid + 256) * 256;
            for (int c = 0; c < 256; c += 4) {
                float4 f0 = *(const float4*)(c0p + c);
                float4 f1 = *(const float4*)(c1p + c);
                float e0[4] = {f0.x, f0.y, f0.z, f0.w};
                float e1[4] = {f1.x, f1.y, f1.z, f1.w};
                #pragma unroll
                for (int cc = 0; cc < 4; cc++) {
                    double d0 = (double)e0[cc], d1 = (double)e1[cc];
                    #pragma unroll
                    for (int r = 0; r < 16; r++) {
                        double rv = rowsd[r][c + cc];
                        a0[r] = fma(d0, rv, a0[r]);
                        a1[r] = fma(d1, rv, a1[r]);
                    }
                }
            }
            double cn0 = cnb[tid], cn1 = cnb[tid + 256];
            #pragma unroll
            for (int r = 0; r < 16; r++) {
                a0[r] = 2.0 * a0[r] - cn0;      // v for code tid
                a1[r] = 2.0 * a1[r] - cn1;      // v for code tid+256
            }
            // per-row argmax across the block (512 codes)
            #pragma unroll
            for (int r = 0; r < 16; r++) {
                double m = a0[r]; int k = tid;
                if (a1[r] > m) { m = a1[r]; k = tid + 256; }
                #pragma unroll
                for (int off = 32; off; off >>= 1) {
                    double om = __shfl_xor(m, off);
                    int ok = __shfl_xor(k, off);
                    if (om > m || (om == m && ok < k)) { m = om; k = ok; }
                }
                if (lane == 0) { redm[wave][r] = m; redk[wave][r] = k; }
            }
            __syncthreads();
            if (tid < 16) {
                double m = redm[0][tid]; int k = redk[0][tid];
                #pragma unroll
                for (int wv = 1; wv < 4; wv++) {
                    double om = redm[wv][tid]; int ok = redk[wv][tid];
                    if (om > m || (om == m && ok < k)) { m = om; k = ok; }
                }
                gmS[tid] = m; gkS[tid] = k;
            }
            __syncthreads();
            #pragma unroll
            for (int r = 0; r < 16; r++) {
                double m = gmS[r];
                double s = exp(a0[r] - m) + exp(a1[r] - m);
                #pragma unroll
                for (int off = 32; off; off >>= 1) s += __shfl_xor(s, off);
                if (lane == 0) reds[wave][r] = s;
            }
            __syncthreads();
            if (tid < nrows) {
                int fr = rl[base + tid];
                double S = ((reds[0][tid] + reds[1][tid]) + reds[2][tid]) + reds[3][tid];
                if (listi == 0) { idx1[fr] = gkS[tid]; prob[fr] = (float)(1.0 / S); }
                else idx2[fr] = gkS[tid];
            }
            __syncthreads();
        }
    }
}

// ---- fuse stage 1: per-pixel scale pick; defer relative-prob-fragile pixels
__launch_bounds__(256)
__global__ void fuse1(const float* __restrict__ feat,
                      const float* __restrict__ prob,
                      const int* __restrict__ idx1, const int* __restrict__ idx2,
                      const float* __restrict__ codebooks,
                      float* __restrict__ out0, float* __restrict__ outZ,
                      float* __restrict__ outS,
                      int* __restrict__ dlist, int* __restrict__ cnt) {
    __shared__ int rsel_s[64], i1_s[64], i2_s[64], defer_s[64];
    int tid = threadIdx.x;
    int b = blockIdx.x >> 6, y = blockIdx.x & 63;

    if (tid < 64) {
        int x = tid;
        int r0 = (b * 64 + y) * 64 + x;
        int r1 = 32768 + (b * 32 + (y >> 1)) * 32 + (x >> 1);
        int r2 = 40960 + (b * 16 + (y >> 2)) * 16 + (x >> 2);
        float p0 = prob[r0], p1 = prob[r1], p2 = prob[r2];
        int rsel = r0; float best = p0;          // strict > keeps first-max
        if (p1 > best) { best = p1; rsel = r1; }
        if (p2 > best) { best = p2; rsel = r2; }
        float second = (rsel == r0) ? fmaxf(p1, p2)
                     : (rsel == r1) ? fmaxf(p0, p2) : fmaxf(p0, p1);
        int defer = (best - second < EPS_P_REL * best) ? 1 : 0;
        defer_s[x] = defer;
        if (defer) {
            int pos = atomicAdd(cnt + 1, 1);
            dlist[pos] = (b << 12) | (y << 6) | x;
            rsel_s[x] = r0; i1_s[x] = 0; i2_s[x] = 0;
        } else {
            int i1 = idx1[rsel], i2 = idx2[r0];
            rsel_s[x] = rsel; i1_s[x] = i1; i2_s[x] = i2;
            size_t zb = (size_t)b * 8192 + (size_t)y * 64 + x;
            outZ[zb] = (float)i1;
            outZ[zb + 4096] = (float)i2;
        }
    }
    __syncthreads();

    int x = tid & 63, cc = tid >> 6;
    int r0 = (b * 64 + y) * 64 + x;
    const float* e0p = feat + (size_t)r0 * 256;
    const float* e1p = feat + (size_t)rsel_s[x] * 256;
    const float* q1p = codebooks + (size_t)i1_s[x] * 256;
    const float* q2p = codebooks + (size_t)(512 + i2_s[x]) * 256;
    int defer = defer_s[x];
    for (int it = 0; it < 64; it++) {
        int c = it * 4 + cc;
        float e0 = e0p[c];
        size_t o = (((size_t)b * 256 + c) * 64 + y) * 64 + x;
        out0[o] = e0;
        if (!defer) {
            float e1 = e1p[c], q1 = q1p[c], q2 = q2p[c];
            float ef = (e1 + e0) * 0.5f;
            float qf = (q1 + q2) * 0.5f;
            outS[o] = ef + (qf - ef);
        }
    }
}

// ---- fuse stage 2: deferred pixels, full fp64 (3 rows x 512 codes each)
__launch_bounds__(256)
__global__ void fuse2(const float* __restrict__ feat,
                      const float* __restrict__ codebooks,
                      const double* __restrict__ cnd,
                      const int* __restrict__ idx2,
                      const int* __restrict__ dlist, const int* __restrict__ cnt,
                      float* __restrict__ outZ, float* __restrict__ outS) {
    __shared__ double sfd[256];
    __shared__ double rv[4]; __shared__ int rk[4]; __shared__ double rs[4];
    __shared__ double gvmax;
    __shared__ double pRes[3]; __shared__ int kRes[3];
    __shared__ int selS, i2S;
    int tid = threadIdx.x;
    int lane = tid & 63, wave = tid >> 6;
    int n = cnt[1];
    for (int e = blockIdx.x; e < n; e += gridDim.x) {
        int px = dlist[e];
        int b = px >> 12, y = (px >> 6) & 63, x = px & 63;
        int r0 = (b * 64 + y) * 64 + x;
        int r1 = 32768 + (b * 32 + (y >> 1)) * 32 + (x >> 1);
        int r2 = 40960 + (b * 16 + (y >> 2)) * 16 + (x >> 2);
        int rows[3] = {r0, r1, r2};
        for (int s3 = 0; s3 < 3; s3++) {
            sfd[tid] = (double)feat[(size_t)rows[s3] * 256 + tid];
            __syncthreads();
            double vloc[2];
            #pragma unroll
            for (int h = 0; h < 2; h++) {
                int k = h * 256 + tid;
                const float* cp = codebooks + (size_t)k * 256;
                double dot = 0.0;
                for (int c = 0; c < 256; c++) dot = fma((double)cp[c], sfd[c], dot);
                vloc[h] = 2.0 * dot - cnd[k];
            }
            double bv = vloc[0]; int bk = tid;
            if (vloc[1] > bv) { bv = vloc[1]; bk = tid + 256; }
            #pragma unroll
            for (int off = 32; off; off >>= 1) {
                double vo = __shfl_xor(bv, off);
                int ko = __shfl_xor(bk, off);
                if (vo > bv || (vo == bv && ko < bk)) { bv = vo; bk = ko; }
            }
            if (lane == 0) { rv[wave] = bv; rk[wave] = bk; }
            __syncthreads();
            if (tid == 0) {
                double v0 = rv[0]; int K = rk[0];
                #pragma unroll
                for (int wv = 1; wv < 4; wv++)
                    if (rv[wv] > v0 || (rv[wv] == v0 && rk[wv] < K)) { v0 = rv[wv]; K = rk[wv]; }
                gvmax = v0; kRes[s3] = K;
            }
            __syncthreads();
            double vm = gvmax;
            double s = exp(vloc[0] - vm) + exp(vloc[1] - vm);
            #pragma unroll
            for (int off = 32; off; off >>= 1) s += __shfl_xor(s, off);
            if (lane == 0) rs[wave] = s;
            __syncthreads();
            if (tid == 0) pRes[s3] = 1.0 / (((rs[0] + rs[1]) + rs[2]) + rs[3]);
            __syncthreads();
        }
        if (tid == 0) {
            int sel = 0; double best = pRes[0];
            if (pRes[1] > best) { best = pRes[1]; sel = 1; }
            if (pRes[2] > best) { best = pRes[2]; sel = 2; }
            selS = sel;
            i2S = idx2[r0];
            size_t zb = (size_t)b * 8192 + (size_t)y * 64 + x;
            outZ[zb] = (float)kRes[sel];
            outZ[zb + 4096] = (float)i2S;
        }
        __syncthreads();
        int sel = selS;
        int c = tid;
        float e0 = feat[(size_t)r0 * 256 + c];
        float e1 = feat[(size_t)rows[sel] * 256 + c];
        float q1 = codebooks[(size_t)kRes[sel] * 256 + c];
        float q2 = codebooks[(size_t)(512 + i2S) * 256 + c];
        float ef = (e1 + e0) * 0.5f;
        float qf = (q1 + q2) * 0.5f;
        size_t o = (((size_t)b * 256 + c) * 64 + y) * 64 + x;
        outS[o] = ef + (qf - ef);
        __syncthreads();
    }
}

extern "C" void kernel_launch(void* const* d_in, const int* in_sizes, int n_in,
                              void* d_out, int out_size, void* d_ws, size_t ws_size,
                              hipStream_t stream) {
    (void)in_sizes; (void)n_in; (void)out_size; (void)ws_size;
    const float* image     = (const float*)d_in[0];   // [8,3,256,256]
    const float* conv_w    = (const float*)d_in[1];   // [256,3,4,4]
    const float* conv_b    = (const float*)d_in[2];   // [256]
    const float* codebooks = (const float*)d_in[3];   // [4,512,256]

    float*  ws    = (float*)d_ws;
    float*  feat  = ws + FEAT_OFF;
    unsigned short* cbs = (unsigned short*)(ws + CBSW_OFF);
    float*  parts = ws + PART_OFF;
    float*  prob  = ws + PROB_OFF;
    int*    idx1  = (int*)(ws + IDX1_OFF);
    int*    idx2  = (int*)(ws + IDX2_OFF);
    float*  cnf   = ws + CNF_OFF;
    double* cnd   = (double*)(ws + CND_OFF);
    float*  img1  = ws + IMG1_OFF;
    float*  img2  = ws + IMG2_OFF;
    int*    rlistA = (int*)(ws + RLA_OFF);
    int*    rlistB = (int*)(ws + RLB_OFF);
    int*    dlist = (int*)(ws + DLIST_OFF);
    int*    cnt   = (int*)(ws + CNT_OFF);

    float* out  = (float*)d_out;
    float* out0 = out;
    float* outZ = out + 8388608;
    float* outS = out + 8454144;

    zero_cnt<<<1, 64, 0, stream>>>(cnt);
    ds_kernel<<<1536, 256, 0, stream>>>(image, img1, 128, 128, 0, 2);
    ds_kernel<<<384, 256, 0, stream>>>(image, img2, 64, 64, 1, 4);
    cnorm_kernel<<<1024, 64, 0, stream>>>(codebooks, cnd, cnf);
    split_cb<<<128, 256, 0, stream>>>(codebooks, cbs);
    encode_all<<<896, 256, 0, stream>>>(image, img1, img2, conv_w, conv_b, feat);
    match_bulk<<<1184, 256, 0, stream>>>(feat, cbs, cnf, parts);
    combine_rows<<<296, 256, 0, stream>>>(parts, idx1, idx2, prob, rlistA, rlistB, cnt);
    rescue_batch<<<256, 256, 0, stream>>>(feat, codebooks, cnd, rlistA, rlistB, cnt, idx1, idx2, prob);
    fuse1<<<512, 256, 0, stream>>>(feat, prob, idx1, idx2, codebooks, out0, outZ, outS, dlist, cnt);
    fuse2<<<512, 256, 0, stream>>>(feat, codebooks, cnd, idx2, dlist, cnt, outZ, outS);
}